// Round 13
// baseline (246.416 us; speedup 1.0000x reference)
//
#include <hip/hip_runtime.h>
#include <hip/hip_bf16.h>

typedef __attribute__((ext_vector_type(8))) short short8;   // 8 bf16 (4 VGPRs)
typedef __attribute__((ext_vector_type(4))) short short4v;  // 4 bf16 (8B)
typedef __attribute__((ext_vector_type(4))) float f32x4;
typedef __attribute__((ext_vector_type(16))) float f32x16;

#define MFMA16(a,b,c) __builtin_amdgcn_mfma_f32_16x16x32_bf16(a,b,c,0,0,0)
#define MFMA32(a,b,c) __builtin_amdgcn_mfma_f32_32x32x16_bf16(a,b,c,0,0,0)

__device__ __forceinline__ unsigned short f2b_rne(float f){
  union { float f; unsigned int u; } v; v.f = f;
  unsigned int u = v.u;
  return (unsigned short)((u + 0x7FFFu + ((u >> 16) & 1u)) >> 16);
}

__device__ __forceinline__ f32x16 zero16(){
  f32x16 z;
  #pragma unroll
  for (int i = 0; i < 16; ++i) z[i] = 0.f;
  return z;
}

// ---------------- convert fp32 -> bf16, 8 elems/thread ----------------
__global__ __launch_bounds__(256) void k_cvt(const float* __restrict__ in,
                                             unsigned short* __restrict__ out, int n8){
  int i = blockIdx.x * 256 + threadIdx.x;
  if (i >= n8) return;
  const float4* p = (const float4*)in + (size_t)i * 2;
  float4 a = p[0], b = p[1];
  short8 o;
  o[0] = (short)f2b_rne(a.x); o[1] = (short)f2b_rne(a.y);
  o[2] = (short)f2b_rne(a.z); o[3] = (short)f2b_rne(a.w);
  o[4] = (short)f2b_rne(b.x); o[5] = (short)f2b_rne(b.y);
  o[6] = (short)f2b_rne(b.z); o[7] = (short)f2b_rne(b.w);
  *((short8*)out + i) = o;
}

// ---------------- transpose + convert: in[R][Cc] f32 -> out[Cc][R] bf16 ----------------
__global__ void k_transpose_cvt(const float* __restrict__ in, unsigned short* __restrict__ out,
                                int R, int Cc){
  __shared__ unsigned short tile[32][33];
  int c0 = blockIdx.x * 32, r0 = blockIdx.y * 32;
  int tx = threadIdx.x, ty = threadIdx.y;   // block (32,8)
  #pragma unroll
  for (int i = 0; i < 32; i += 8)
    tile[ty + i][tx] = f2b_rne(in[(size_t)(r0 + ty + i) * Cc + c0 + tx]);
  __syncthreads();
  #pragma unroll
  for (int i = 0; i < 32; i += 8)
    out[(size_t)(c0 + ty + i) * R + r0 + tx] = tile[tx][ty + i];
}

// ---------------- QKV GEMM: xb[8192][768] @ wqkvt[2304][768]^T, scatter q/k/vt ----------------
__global__ __launch_bounds__(256) void k_gemm_qkv(
    const unsigned short* __restrict__ A,     // xb
    const unsigned short* __restrict__ Bt,    // wqkvt [j][c]
    unsigned short* __restrict__ qbuf,        // [B*H][4096][96], pre-scaled (Dh^-0.5 * log2e)
    unsigned short* __restrict__ kbuf,        // [B*H][4096][96]
    unsigned short* __restrict__ vtb)         // [B*H][96][4096]
{
  __shared__ short As[128 * 40];   // rows padded 32->40 elems (80B stride)
  __shared__ short Bs[128 * 40];
  int m0 = blockIdx.x * 128, n0 = blockIdx.y * 128;
  int t = threadIdx.x, l = t & 63, w = t >> 6;
  int lr = l & 15, lh = l >> 4;
  int wr = w >> 1, wc = w & 1;

  int row0 = t >> 2, cs0 = t & 3;
  int row1 = row0 + 64;
  const unsigned short* ga0 = A  + (size_t)(m0 + row0) * 768 + cs0 * 8;
  const unsigned short* ga1 = A  + (size_t)(m0 + row1) * 768 + cs0 * 8;
  const unsigned short* gb0 = Bt + (size_t)(n0 + row0) * 768 + cs0 * 8;
  const unsigned short* gb1 = Bt + (size_t)(n0 + row1) * 768 + cs0 * 8;
  short* la0 = As + row0 * 40 + cs0 * 8;
  short* la1 = As + row1 * 40 + cs0 * 8;
  short* lb0 = Bs + row0 * 40 + cs0 * 8;
  short* lb1 = Bs + row1 * 40 + cs0 * 8;

  f32x4 acc[4][4];
  f32x4 z4 = {0.f, 0.f, 0.f, 0.f};
  #pragma unroll
  for (int mf = 0; mf < 4; ++mf)
    #pragma unroll
    for (int nf = 0; nf < 4; ++nf) acc[mf][nf] = z4;

  short8 ra0 = *(const short8*)ga0;
  short8 ra1 = *(const short8*)ga1;
  short8 rb0 = *(const short8*)gb0;
  short8 rb1 = *(const short8*)gb1;

  for (int kt = 0; kt < 24; ++kt){
    __syncthreads();
    *(short8*)la0 = ra0; *(short8*)la1 = ra1;
    *(short8*)lb0 = rb0; *(short8*)lb1 = rb1;
    __syncthreads();
    if (kt < 23){
      ra0 = *(const short8*)(ga0 + (kt + 1) * 32);
      ra1 = *(const short8*)(ga1 + (kt + 1) * 32);
      rb0 = *(const short8*)(gb0 + (kt + 1) * 32);
      rb1 = *(const short8*)(gb1 + (kt + 1) * 32);
    }
    short8 af[4], bfm[4];
    #pragma unroll
    for (int mf = 0; mf < 4; ++mf)
      af[mf] = *(const short8*)(As + (wr * 64 + mf * 16 + lr) * 40 + lh * 8);
    #pragma unroll
    for (int nf = 0; nf < 4; ++nf)
      bfm[nf] = *(const short8*)(Bs + (wc * 64 + nf * 16 + lr) * 40 + lh * 8);
    #pragma unroll
    for (int mf = 0; mf < 4; ++mf)
      #pragma unroll
      for (int nf = 0; nf < 4; ++nf)
        acc[mf][nf] = MFMA16(af[mf], bfm[nf], acc[mf][nf]);
  }

  // Dh^-0.5 * log2(e) folded into Q so attention can use exp2
  const float qscale = 0.10206207261596577f * 1.4426950408889634f;
  int three = n0 / 768;            // uniform per block (768 % 128 == 0)
  int b_ = m0 >> 12;               // block rows stay within one batch
  int ntok0 = m0 & 4095;
  #pragma unroll
  for (int nf = 0; nf < 4; ++nf){
    int gcol = n0 + wc * 64 + nf * 16 + lr;
    int jj = gcol - three * 768;
    int h = jj / 96;
    int dh = jj - h * 96;
    #pragma unroll
    for (int mf = 0; mf < 4; ++mf){
      int ntok = ntok0 + wr * 64 + mf * 16 + lh * 4;
      if (three == 0){
        unsigned short* dst = qbuf + (size_t)(b_ * 8 + h) * 4096 * 96;
        #pragma unroll
        for (int r = 0; r < 4; ++r)
          dst[(size_t)(ntok + r) * 96 + dh] = f2b_rne(acc[mf][nf][r] * qscale);
      } else if (three == 1){
        unsigned short* dst = kbuf + (size_t)(b_ * 8 + h) * 4096 * 96;
        #pragma unroll
        for (int r = 0; r < 4; ++r)
          dst[(size_t)(ntok + r) * 96 + dh] = f2b_rne(acc[mf][nf][r]);
      } else {
        short4v sv;
        #pragma unroll
        for (int r = 0; r < 4; ++r) sv[r] = (short)f2b_rne(acc[mf][nf][r]);
        *(short4v*)(vtb + ((size_t)(b_ * 8 + h) * 96 + dh) * 4096 + ntok) = sv;
      }
    }
  }
}

// ---------------- flash attention v13: fixed-base softmax + 2-way KV-split, 4 waves/SIMD ----
// grid (16 bh, 32 qt) = 512 blocks, 512 threads = 8 waves = 4 qquads x 2 sets; q-tile 128.
// 2 blocks/CU (LDS 54KB each) -> 16 waves/CU = 4 waves/SIMD (v12 was grid-limited at 2).
// NO waves_per_eu attribute: v12's lean fixed-base body compiles to 80 VGPR naturally, and
// 80 < 128 so 4 waves/SIMD fit without allocator games (rounds 3-11 lesson).
// Set s handles kv tiles 2*ss+s (64 rows each), 32 supersteps; single-buffered slot per set,
// 2 barriers/superstep (v6-verified scheme). Fixed base => merge is PLAIN ADDS.
__global__ __launch_bounds__(512) void k_attn13(
    const unsigned short* __restrict__ qb,
    const unsigned short* __restrict__ kb,
    const unsigned short* __restrict__ vtb,
    unsigned short* __restrict__ ao)      // [B*4096][768] bf16
{
  // LDS (shorts): K slot s at s*6656 (64 rows x 104); V slot s at 13312 + s*6912 (96 rows x 72)
  __shared__ short lds[27136];    // 54272 B; reused as f32 merge scratch at the end
  const int bh = blockIdx.x;      // same-bh blocks share an XCD (L2 locality for K/V)
  const int qt = blockIdx.y;
  const int tid = threadIdx.x;
  const int ln = tid & 63, wid = tid >> 6;
  const int qc = ln & 31, hi = ln >> 5;
  const int set = wid >> 2, qquad = wid & 3;
  const int q0 = qt * 128 + qquad * 32;

  const unsigned short* qbase = qb  + (size_t)bh * 4096 * 96;
  const unsigned short* kbase = kb  + (size_t)bh * 4096 * 96;
  const unsigned short* vbase = vtb + (size_t)bh * 96 * 4096;

  // Q B-fragments: lane holds Q[q0+qc][kw*16 + hi*8 + e]
  short8 qf[6];
  #pragma unroll
  for (int kw = 0; kw < 6; ++kw)
    qf[kw] = *(const short8*)(qbase + (size_t)(q0 + qc) * 96 + kw * 16 + hi * 8);

  // staging: 3072 x 16B chunks / superstep (2 tiles x (K 768 + V 768)); 6 per thread.
  // j=0..2: K chunks; j=3..5: V chunks (v6/v7-verified formulas).
  const unsigned short* gp[6]; int loff[6];
  #pragma unroll
  for (int j = 0; j < 3; ++j){
    int ck = tid + j * 512;                 // [0,1536)
    int s = (ck >= 768) ? 1 : 0;
    int cc = ck - s * 768;
    int r = cc / 12, cl = cc - r * 12;
    gp[j] = kbase + (size_t)(s * 64 + r) * 96 + cl * 8;
    loff[j] = s * 6656 + r * 104 + cl * 8;
  }
  #pragma unroll
  for (int j = 3; j < 6; ++j){
    int cv = tid + (j - 3) * 512;           // [0,1536)
    int s = (cv >= 768) ? 1 : 0;
    int cc = cv - s * 768;
    int r = cc >> 3, cl = cc & 7;
    gp[j] = vbase + (size_t)r * 4096 + s * 64 + cl * 8;
    loff[j] = 13312 + s * 6912 + r * 72 + cl * 8;
  }

  short8 rs[6];
  #pragma unroll
  for (int j = 0; j < 6; ++j) rs[j] = *(const short8*)gp[j];
  #pragma unroll
  for (int j = 0; j < 3; ++j) gp[j] += 12288;                 // 128 kv rows ahead
  #pragma unroll
  for (int j = 3; j < 6; ++j) gp[j] += 128;                   // 128 kv cols ahead
  #pragma unroll
  for (int j = 0; j < 6; ++j) *(short8*)(lds + loff[j]) = rs[j];

  f32x16 oacc[3];
  #pragma unroll
  for (int dt = 0; dt < 3; ++dt) oacc[dt] = zero16();
  float lsum = 0.f;               // per-lane partial denominator

  const short* Kb = lds + set * 6656 + qc * 104 + hi * 8;
  const short* Vb = lds + 13312 + set * 6912 + qc * 72 + hi * 8;

#define CVTPK(d, lo_, hi_) asm("v_cvt_pk_bf16_f32 %0, %1, %2" : "=v"(d) : "v"(lo_), "v"(hi_))
#define PLSWAP(x_, y_)     asm("v_permlane32_swap_b32 %0, %1" : "+v"(x_), "+v"(y_))

  for (int ss = 0; ss < 32; ++ss){
    __syncthreads();   // staged writes for this superstep visible

    // issue next superstep's global loads early (latency hides under compute)
    if (ss < 31){
      #pragma unroll
      for (int j = 0; j < 3; ++j){ rs[j] = *(const short8*)gp[j]; gp[j] += 12288; }
      #pragma unroll
      for (int j = 3; j < 6; ++j){ rs[j] = *(const short8*)gp[j]; gp[j] += 128; }
    }

    // ---- QK^T: S^T[k][q], two 32-k subtiles of this set's 64-kv tile ----
    f32x16 s0 = zero16(), s1 = zero16();
    __builtin_amdgcn_s_setprio(1);
    #pragma unroll
    for (int kw = 0; kw < 6; ++kw){
      short8 kf = *(const short8*)(Kb + kw * 16);
      s0 = MFMA32(kf, qf[kw], s0);
    }
    #pragma unroll
    for (int kw = 0; kw < 6; ++kw){
      short8 kf = *(const short8*)(Kb + 3328 + kw * 16);   // +32 rows
      s1 = MFMA32(kf, qf[kw], s1);
    }
    __builtin_amdgcn_s_setprio(0);

    // ---- fixed-base softmax: P = 2^(S-12); no max, no shfl, no branch ----
    {
      float p0 = 0.f, p1 = 0.f, p2 = 0.f, p3 = 0.f;
      #pragma unroll
      for (int r = 0; r < 16; r += 4){
        s0[r]   = exp2f(s0[r]   - 12.0f); p0 += s0[r];
        s0[r+1] = exp2f(s0[r+1] - 12.0f); p1 += s0[r+1];
        s0[r+2] = exp2f(s0[r+2] - 12.0f); p2 += s0[r+2];
        s0[r+3] = exp2f(s0[r+3] - 12.0f); p3 += s0[r+3];
      }
      #pragma unroll
      for (int r = 0; r < 16; r += 4){
        s1[r]   = exp2f(s1[r]   - 12.0f); p0 += s1[r];
        s1[r+1] = exp2f(s1[r+1] - 12.0f); p1 += s1[r+1];
        s1[r+2] = exp2f(s1[r+2] - 12.0f); p2 += s1[r+2];
        s1[r+3] = exp2f(s1[r+3] - 12.0f); p3 += s1[r+3];
      }
      lsum += (p0 + p1) + (p2 + p3);
    }

    // ---- P^T -> bf16 B-frags: 16 cvt_pk + 8 permlane32_swap ----
    short8 pa[4];
    {
      unsigned int a, b;
      union { unsigned int u[4]; short8 s; } pk;
      CVTPK(a, s0[0], s0[1]);  CVTPK(b, s0[4],  s0[5]);  PLSWAP(a, b); pk.u[0] = a; pk.u[2] = b;
      CVTPK(a, s0[2], s0[3]);  CVTPK(b, s0[6],  s0[7]);  PLSWAP(a, b); pk.u[1] = a; pk.u[3] = b;
      pa[0] = pk.s;
      CVTPK(a, s0[8], s0[9]);  CVTPK(b, s0[12], s0[13]); PLSWAP(a, b); pk.u[0] = a; pk.u[2] = b;
      CVTPK(a, s0[10], s0[11]); CVTPK(b, s0[14], s0[15]); PLSWAP(a, b); pk.u[1] = a; pk.u[3] = b;
      pa[1] = pk.s;
      CVTPK(a, s1[0], s1[1]);  CVTPK(b, s1[4],  s1[5]);  PLSWAP(a, b); pk.u[0] = a; pk.u[2] = b;
      CVTPK(a, s1[2], s1[3]);  CVTPK(b, s1[6],  s1[7]);  PLSWAP(a, b); pk.u[1] = a; pk.u[3] = b;
      pa[2] = pk.s;
      CVTPK(a, s1[8], s1[9]);  CVTPK(b, s1[12], s1[13]); PLSWAP(a, b); pk.u[0] = a; pk.u[2] = b;
      CVTPK(a, s1[10], s1[11]); CVTPK(b, s1[14], s1[15]); PLSWAP(a, b); pk.u[1] = a; pk.u[3] = b;
      pa[3] = pk.s;
    }

    // ---- PV: O^T[d][q] += V^T-frag x P-frag ----
    __builtin_amdgcn_s_setprio(1);
    #pragma unroll
    for (int dt = 0; dt < 3; ++dt){
      #pragma unroll
      for (int w = 0; w < 4; ++w){
        short8 vf = *(const short8*)(Vb + dt * 2304 + w * 16);
        oacc[dt] = MFMA32(vf, pa[w], oacc[dt]);
      }
    }
    __builtin_amdgcn_s_setprio(0);

    __syncthreads();   // all LDS reads of this superstep done
    if (ss < 31){
      #pragma unroll
      for (int j = 0; j < 6; ++j) *(short8*)(lds + loff[j]) = rs[j];
    }
  }

  // ---- merge set-1 partials into set-0 via LDS: plain adds (fixed base => no weights) ----
  float* fl = (float*)lds;
  {
    __syncthreads();
    if (set == 1){
      #pragma unroll
      for (int dt = 0; dt < 3; ++dt)
        #pragma unroll
        for (int r = 0; r < 16; ++r)
          fl[qquad * 3072 + dt * 1024 + r * 64 + ln] = oacc[dt][r];
      fl[12288 + qquad * 64 + ln] = lsum;
    }
    __syncthreads();
    if (set == 0){
      lsum += fl[12288 + qquad * 64 + ln];
      #pragma unroll
      for (int dt = 0; dt < 3; ++dt)
        #pragma unroll
        for (int r = 0; r < 16; ++r)
          oacc[dt][r] += fl[qquad * 3072 + dt * 1024 + r * 64 + ln];
    }
  }

  // ---- epilogue (set 0 only): combine lane^32 denominators, normalize, write bf16 ----
  if (set == 0){
    float lt = lsum + __shfl_xor(lsum, 32, 64);
    float inv = 1.0f / lt;
    int b_ = bh >> 3, h = bh & 7;
    unsigned short* orow = ao + (size_t)(b_ * 4096 + q0 + qc) * 768 + h * 96;
    #pragma unroll
    for (int dt = 0; dt < 3; ++dt)
      #pragma unroll
      for (int g4 = 0; g4 < 4; ++g4){
        short4v sv;
        #pragma unroll
        for (int r = 0; r < 4; ++r) sv[r] = (short)f2b_rne(oacc[dt][g4 * 4 + r] * inv);
        *(short4v*)(orow + dt * 32 + g4 * 8 + hi * 4) = sv;
      }
  }
#undef CVTPK
#undef PLSWAP
}

// ---------------- proj GEMM: ao[8192][768] @ wprojt[768][768]^T + bias -> f32 out ----------------
__global__ __launch_bounds__(256) void k_gemm_proj(
    const unsigned short* __restrict__ A,
    const unsigned short* __restrict__ Bt,
    const float* __restrict__ bias,
    float* __restrict__ out)
{
  __shared__ short As[128 * 40];
  __shared__ short Bs[128 * 40];
  int m0 = blockIdx.x * 128, n0 = blockIdx.y * 128;
  int t = threadIdx.x, l = t & 63, w = t >> 6;
  int lr = l & 15, lh = l >> 4;
  int wr = w >> 1, wc = w & 1;

  int row0 = t >> 2, cs0 = t & 3;
  int row1 = row0 + 64;
  const unsigned short* ga0 = A  + (size_t)(m0 + row0) * 768 + cs0 * 8;
  const unsigned short* ga1 = A  + (size_t)(m0 + row1) * 768 + cs0 * 8;
  const unsigned short* gb0 = Bt + (size_t)(n0 + row0) * 768 + cs0 * 8;
  const unsigned short* gb1 = Bt + (size_t)(n0 + row1) * 768 + cs0 * 8;
  short* la0 = As + row0 * 40 + cs0 * 8;
  short* la1 = As + row1 * 40 + cs0 * 8;
  short* lb0 = Bs + row0 * 40 + cs0 * 8;
  short* lb1 = Bs + row1 * 40 + cs0 * 8;

  f32x4 acc[4][4];
  f32x4 z4 = {0.f, 0.f, 0.f, 0.f};
  #pragma unroll
  for (int mf = 0; mf < 4; ++mf)
    #pragma unroll
    for (int nf = 0; nf < 4; ++nf) acc[mf][nf] = z4;

  short8 ra0 = *(const short8*)ga0;
  short8 ra1 = *(const short8*)ga1;
  short8 rb0 = *(const short8*)gb0;
  short8 rb1 = *(const short8*)gb1;

  for (int kt = 0; kt < 24; ++kt){
    __syncthreads();
    *(short8*)la0 = ra0; *(short8*)la1 = ra1;
    *(short8*)lb0 = rb0; *(short8*)lb1 = rb1;
    __syncthreads();
    if (kt < 23){
      ra0 = *(const short8*)(ga0 + (kt + 1) * 32);
      ra1 = *(const short8*)(ga1 + (kt + 1) * 32);
      rb0 = *(const short8*)(gb0 + (kt + 1) * 32);
      rb1 = *(const short8*)(gb1 + (kt + 1) * 32);
    }
    short8 af[4], bfm[4];
    #pragma unroll
    for (int mf = 0; mf < 4; ++mf)
      af[mf] = *(const short8*)(As + (wr * 64 + mf * 16 + lr) * 40 + lh * 8);
    #pragma unroll
    for (int nf = 0; nf < 4; ++nf)
      bfm[nf] = *(const short8*)(Bs + (wc * 64 + nf * 16 + lr) * 40 + lh * 8);
    #pragma unroll
    for (int mf = 0; mf < 4; ++mf)
      #pragma unroll
      for (int nf = 0; nf < 4; ++nf)
        acc[mf][nf] = MFMA16(af[mf], bfm[nf], acc[mf][nf]);
  }

  #pragma unroll
  for (int nf = 0; nf < 4; ++nf){
    int gcol = n0 + wc * 64 + nf * 16 + lr;
    float bb = bias[gcol];
    #pragma unroll
    for (int mf = 0; mf < 4; ++mf){
      int grow = m0 + wr * 64 + mf * 16 + lh * 4;
      #pragma unroll
      for (int r = 0; r < 4; ++r)
        out[(size_t)(grow + r) * 768 + gcol] = acc[mf][nf][r] + bb;
    }
  }
}

extern "C" void kernel_launch(void* const* d_in, const int* in_sizes, int n_in,
                              void* d_out, int out_size, void* d_ws, size_t ws_size,
                              hipStream_t stream) {
  const float* x      = (const float*)d_in[0];
  const float* w_qkv  = (const float*)d_in[1];
  const float* w_proj = (const float*)d_in[2];
  const float* b_proj = (const float*)d_in[3];
  float* out = (float*)d_out;
  char* ws = (char*)d_ws;

  // workspace layout (all 16B-aligned); ao aliases xb (xb dead after qkv gemm)
  unsigned short* xb     = (unsigned short*)(ws);                 // 12,582,912 B
  unsigned short* wqkvt  = (unsigned short*)(ws + 12582912);      //  3,538,944 B
  unsigned short* wprojt = (unsigned short*)(ws + 16121856);      //  1,179,648 B
  unsigned short* qbuf   = (unsigned short*)(ws + 17301504);      // 12,582,912 B
  unsigned short* kbuf   = (unsigned short*)(ws + 29884416);      // 12,582,912 B
  unsigned short* vtb    = (unsigned short*)(ws + 42467328);      // 12,582,912 B
  unsigned short* aob    = xb;                                    // reuse

  k_cvt<<<3072, 256, 0, stream>>>(x, xb, 786432);                       // 2*4096*768 / 8
  k_transpose_cvt<<<dim3(72, 24), dim3(32, 8), 0, stream>>>(w_qkv, wqkvt, 768, 2304);
  k_transpose_cvt<<<dim3(24, 24), dim3(32, 8), 0, stream>>>(w_proj, wprojt, 768, 768);
  k_gemm_qkv<<<dim3(64, 18), 256, 0, stream>>>(xb, wqkvt, qbuf, kbuf, vtb);
  k_attn13<<<dim3(16, 32), 512, 0, stream>>>(qbuf, kbuf, vtb, aob);
  k_gemm_proj<<<dim3(64, 6), 256, 0, stream>>>(aob, wprojt, b_proj, out);
}

// Round 14
// 216.070 us; speedup vs baseline: 1.1404x; 1.1404x over previous
//
#include <hip/hip_runtime.h>
#include <hip/hip_bf16.h>

typedef __attribute__((ext_vector_type(8))) short short8;   // 8 bf16 (4 VGPRs)
typedef __attribute__((ext_vector_type(4))) short short4v;  // 4 bf16 (8B)
typedef __attribute__((ext_vector_type(4))) float f32x4;
typedef __attribute__((ext_vector_type(16))) float f32x16;

#define MFMA16(a,b,c) __builtin_amdgcn_mfma_f32_16x16x32_bf16(a,b,c,0,0,0)
#define MFMA32(a,b,c) __builtin_amdgcn_mfma_f32_32x32x16_bf16(a,b,c,0,0,0)

__device__ __forceinline__ unsigned short f2b_rne(float f){
  union { float f; unsigned int u; } v; v.f = f;
  unsigned int u = v.u;
  return (unsigned short)((u + 0x7FFFu + ((u >> 16) & 1u)) >> 16);
}

// pack 8 f32 (two float4) -> short8 bf16, SAME scalar f2b_rne path as the old k_cvt
__device__ __forceinline__ short8 pack8f(float4 a, float4 b){
  short8 o;
  o[0] = (short)f2b_rne(a.x); o[1] = (short)f2b_rne(a.y);
  o[2] = (short)f2b_rne(a.z); o[3] = (short)f2b_rne(a.w);
  o[4] = (short)f2b_rne(b.x); o[5] = (short)f2b_rne(b.y);
  o[6] = (short)f2b_rne(b.z); o[7] = (short)f2b_rne(b.w);
  return o;
}

__device__ __forceinline__ f32x16 zero16(){
  f32x16 z;
  #pragma unroll
  for (int i = 0; i < 16; ++i) z[i] = 0.f;
  return z;
}

// ---------------- transpose + convert both weights: z=0 w_qkv[768][2304], z=1 w_proj[768][768]
__global__ void k_transpose_cvt2(const float* __restrict__ wqkv, const float* __restrict__ wproj,
                                 unsigned short* __restrict__ oqkv, unsigned short* __restrict__ oproj){
  __shared__ unsigned short tile[32][33];
  const float* in; unsigned short* out; int Cc;
  if (blockIdx.z == 0){ in = wqkv; out = oqkv; Cc = 2304; }
  else {
    if (blockIdx.x >= 24) return;
    in = wproj; out = oproj; Cc = 768;
  }
  int c0 = blockIdx.x * 32, r0 = blockIdx.y * 32;
  int tx = threadIdx.x, ty = threadIdx.y;   // block (32,8)
  #pragma unroll
  for (int i = 0; i < 32; i += 8)
    tile[ty + i][tx] = f2b_rne(in[(size_t)(r0 + ty + i) * Cc + c0 + tx]);
  __syncthreads();
  #pragma unroll
  for (int i = 0; i < 32; i += 8)
    out[(size_t)(c0 + ty + i) * 768 + r0 + tx] = tile[tx][ty + i];
}

// ---------------- QKV GEMM: x[8192][768] f32 (inline cvt) @ wqkvt[2304][768]^T, scatter ------
__global__ __launch_bounds__(256) void k_gemm_qkv(
    const float* __restrict__ X,              // fp32 input, converted inline via f2b_rne
    const unsigned short* __restrict__ Bt,    // wqkvt [j][c]
    unsigned short* __restrict__ qbuf,        // [B*H][4096][96], pre-scaled (Dh^-0.5 * log2e)
    unsigned short* __restrict__ kbuf,        // [B*H][4096][96]
    unsigned short* __restrict__ vtb)         // [B*H][96][4096]
{
  __shared__ short As[128 * 40];   // rows padded 32->40 elems (80B stride)
  __shared__ short Bs[128 * 40];
  int m0 = blockIdx.x * 128, n0 = blockIdx.y * 128;
  int t = threadIdx.x, l = t & 63, w = t >> 6;
  int lr = l & 15, lh = l >> 4;
  int wr = w >> 1, wc = w & 1;

  int row0 = t >> 2, cs0 = t & 3;
  int row1 = row0 + 64;
  const float* ga0 = X + (size_t)(m0 + row0) * 768 + cs0 * 8;
  const float* ga1 = X + (size_t)(m0 + row1) * 768 + cs0 * 8;
  const unsigned short* gb0 = Bt + (size_t)(n0 + row0) * 768 + cs0 * 8;
  const unsigned short* gb1 = Bt + (size_t)(n0 + row1) * 768 + cs0 * 8;
  short* la0 = As + row0 * 40 + cs0 * 8;
  short* la1 = As + row1 * 40 + cs0 * 8;
  short* lb0 = Bs + row0 * 40 + cs0 * 8;
  short* lb1 = Bs + row1 * 40 + cs0 * 8;

  f32x4 acc[4][4];
  f32x4 z4 = {0.f, 0.f, 0.f, 0.f};
  #pragma unroll
  for (int mf = 0; mf < 4; ++mf)
    #pragma unroll
    for (int nf = 0; nf < 4; ++nf) acc[mf][nf] = z4;

  float4 fa0 = *(const float4*)ga0, fa0b = *(const float4*)(ga0 + 4);
  float4 fa1 = *(const float4*)ga1, fa1b = *(const float4*)(ga1 + 4);
  short8 rb0 = *(const short8*)gb0;
  short8 rb1 = *(const short8*)gb1;

  for (int kt = 0; kt < 24; ++kt){
    short8 ra0 = pack8f(fa0, fa0b);
    short8 ra1 = pack8f(fa1, fa1b);
    __syncthreads();
    *(short8*)la0 = ra0; *(short8*)la1 = ra1;
    *(short8*)lb0 = rb0; *(short8*)lb1 = rb1;
    __syncthreads();
    if (kt < 23){
      fa0 = *(const float4*)(ga0 + (kt + 1) * 32); fa0b = *(const float4*)(ga0 + (kt + 1) * 32 + 4);
      fa1 = *(const float4*)(ga1 + (kt + 1) * 32); fa1b = *(const float4*)(ga1 + (kt + 1) * 32 + 4);
      rb0 = *(const short8*)(gb0 + (kt + 1) * 32);
      rb1 = *(const short8*)(gb1 + (kt + 1) * 32);
    }
    short8 af[4], bfm[4];
    #pragma unroll
    for (int mf = 0; mf < 4; ++mf)
      af[mf] = *(const short8*)(As + (wr * 64 + mf * 16 + lr) * 40 + lh * 8);
    #pragma unroll
    for (int nf = 0; nf < 4; ++nf)
      bfm[nf] = *(const short8*)(Bs + (wc * 64 + nf * 16 + lr) * 40 + lh * 8);
    #pragma unroll
    for (int mf = 0; mf < 4; ++mf)
      #pragma unroll
      for (int nf = 0; nf < 4; ++nf)
        acc[mf][nf] = MFMA16(af[mf], bfm[nf], acc[mf][nf]);
  }

  // Dh^-0.5 * log2(e) folded into Q so attention can use exp2
  const float qscale = 0.10206207261596577f * 1.4426950408889634f;
  int three = n0 / 768;            // uniform per block (768 % 128 == 0)
  int b_ = m0 >> 12;               // block rows stay within one batch
  int ntok0 = m0 & 4095;
  #pragma unroll
  for (int nf = 0; nf < 4; ++nf){
    int gcol = n0 + wc * 64 + nf * 16 + lr;
    int jj = gcol - three * 768;
    int h = jj / 96;
    int dh = jj - h * 96;
    #pragma unroll
    for (int mf = 0; mf < 4; ++mf){
      int ntok = ntok0 + wr * 64 + mf * 16 + lh * 4;
      if (three == 0){
        unsigned short* dst = qbuf + (size_t)(b_ * 8 + h) * 4096 * 96;
        #pragma unroll
        for (int r = 0; r < 4; ++r)
          dst[(size_t)(ntok + r) * 96 + dh] = f2b_rne(acc[mf][nf][r] * qscale);
      } else if (three == 1){
        unsigned short* dst = kbuf + (size_t)(b_ * 8 + h) * 4096 * 96;
        #pragma unroll
        for (int r = 0; r < 4; ++r)
          dst[(size_t)(ntok + r) * 96 + dh] = f2b_rne(acc[mf][nf][r]);
      } else {
        short4v sv;
        #pragma unroll
        for (int r = 0; r < 4; ++r) sv[r] = (short)f2b_rne(acc[mf][nf][r]);
        *(short4v*)(vtb + ((size_t)(b_ * 8 + h) * 96 + dh) * 4096 + ntok) = sv;
      }
    }
  }
}

// ---------------- flash attention v12 (unchanged, verified 153us): fixed-base softmax --------
// grid (16 bh, 16 qt), 512 threads = 8 waves x 32 q each; KVBLK=64, 64 steps; LDS
// double-buffered, ONE barrier/step. 80 VGPR, zero scratch. P = exp2(S-12): no max/shfl/
// vote/rescale; per-lane denominator, lane^32 combine in epilogue.
__global__ __launch_bounds__(512) void k_attn12(
    const unsigned short* __restrict__ qb,
    const unsigned short* __restrict__ kb,
    const unsigned short* __restrict__ vtb,
    unsigned short* __restrict__ ao)      // [B*4096][768] bf16
{
  // LDS (shorts): K buf b at b*6656 (64 rows x 104); V buf b at 13312 + b*6912 (96 rows x 72)
  __shared__ short lds[27136];    // 54272 B
  const int bh = blockIdx.x;      // same-bh blocks share an XCD (L2 locality for K/V)
  const int qt = blockIdx.y;
  const int tid = threadIdx.x;
  const int ln = tid & 63, wid = tid >> 6;
  const int qc = ln & 31, hi = ln >> 5;
  const int q0 = qt * 256 + wid * 32;

  const unsigned short* qbase = qb  + (size_t)bh * 4096 * 96;
  const unsigned short* kbase = kb  + (size_t)bh * 4096 * 96;
  const unsigned short* vbase = vtb + (size_t)bh * 96 * 4096;

  // Q B-fragments hoisted: lane holds Q[q0+qc][kw*16 + hi*8 + e]
  short8 qf[6];
  #pragma unroll
  for (int kw = 0; kw < 6; ++kw)
    qf[kw] = *(const short8*)(qbase + (size_t)(q0 + qc) * 96 + kw * 16 + hi * 8);

  // staging: 1536 x 16B chunks (K: 768, V^T: 768); 3 per thread
  const unsigned short* gp[3]; int gstep[3], loff[3], lstep[3];
  #pragma unroll
  for (int j = 0; j < 3; ++j){
    int c = tid + j * 512;
    if (c < 768){
      int r = c / 12, cl = c - r * 12;
      gp[j] = kbase + r * 96 + cl * 8; gstep[j] = 64 * 96;
      loff[j] = r * 104 + cl * 8;      lstep[j] = 6656;
    } else {
      int cv = c - 768; int r = cv >> 3, cl = cv & 7;
      gp[j] = vbase + (size_t)r * 4096 + cl * 8; gstep[j] = 64;
      loff[j] = 13312 + r * 72 + cl * 8;         lstep[j] = 6912;
    }
  }

  short8 rs[3];
  #pragma unroll
  for (int j = 0; j < 3; ++j){ rs[j] = *(const short8*)gp[j]; gp[j] += gstep[j]; }
  #pragma unroll
  for (int j = 0; j < 3; ++j) *(short8*)(lds + loff[j]) = rs[j];   // buf 0

  f32x16 oacc[3];
  #pragma unroll
  for (int dt = 0; dt < 3; ++dt) oacc[dt] = zero16();
  float lsum = 0.f;               // per-lane partial denominator (lane^32 combined at end)

  const int krd = qc * 104 + hi * 8;          // K A-frag lane base (within buf)
  const int vrd = 13312 + qc * 72 + hi * 8;   // V A-frag lane base (buf0 base folded in)

#define CVTPK(d, lo_, hi_) asm("v_cvt_pk_bf16_f32 %0, %1, %2" : "=v"(d) : "v"(lo_), "v"(hi_))
#define PLSWAP(x_, y_)     asm("v_permlane32_swap_b32 %0, %1" : "+v"(x_), "+v"(y_))

  for (int kt = 0; kt < 64; ++kt){
    const int cur = kt & 1;
    __syncthreads();
    // issue next tile's global loads early (latency hides under compute)
    if (kt < 63){
      #pragma unroll
      for (int j = 0; j < 3; ++j){ rs[j] = *(const short8*)gp[j]; gp[j] += gstep[j]; }
    }
    const short* Kb = lds + cur * 6656 + krd;
    const short* Vb = lds + cur * 6912 + vrd;

    // ---- QK^T: S^T[k][q], two 32-k subtiles ----
    f32x16 s0 = zero16(), s1 = zero16();
    __builtin_amdgcn_s_setprio(1);
    #pragma unroll
    for (int kw = 0; kw < 6; ++kw){
      short8 kf = *(const short8*)(Kb + kw * 16);
      s0 = MFMA32(kf, qf[kw], s0);
    }
    #pragma unroll
    for (int kw = 0; kw < 6; ++kw){
      short8 kf = *(const short8*)(Kb + 3328 + kw * 16);
      s1 = MFMA32(kf, qf[kw], s1);
    }
    __builtin_amdgcn_s_setprio(0);

    // ---- fixed-base softmax: P = 2^(S-12); no max, no shfl, no branch ----
    {
      float p0 = 0.f, p1 = 0.f, p2 = 0.f, p3 = 0.f;
      #pragma unroll
      for (int r = 0; r < 16; r += 4){
        s0[r]   = exp2f(s0[r]   - 12.0f); p0 += s0[r];
        s0[r+1] = exp2f(s0[r+1] - 12.0f); p1 += s0[r+1];
        s0[r+2] = exp2f(s0[r+2] - 12.0f); p2 += s0[r+2];
        s0[r+3] = exp2f(s0[r+3] - 12.0f); p3 += s0[r+3];
      }
      #pragma unroll
      for (int r = 0; r < 16; r += 4){
        s1[r]   = exp2f(s1[r]   - 12.0f); p0 += s1[r];
        s1[r+1] = exp2f(s1[r+1] - 12.0f); p1 += s1[r+1];
        s1[r+2] = exp2f(s1[r+2] - 12.0f); p2 += s1[r+2];
        s1[r+3] = exp2f(s1[r+3] - 12.0f); p3 += s1[r+3];
      }
      lsum += (p0 + p1) + (p2 + p3);
    }

    // ---- P^T -> bf16 B-frags: 16 cvt_pk + 8 permlane32_swap ----
    short8 pa[4];
    {
      unsigned int a, b;
      union { unsigned int u[4]; short8 s; } pk;
      CVTPK(a, s0[0], s0[1]);  CVTPK(b, s0[4],  s0[5]);  PLSWAP(a, b); pk.u[0] = a; pk.u[2] = b;
      CVTPK(a, s0[2], s0[3]);  CVTPK(b, s0[6],  s0[7]);  PLSWAP(a, b); pk.u[1] = a; pk.u[3] = b;
      pa[0] = pk.s;
      CVTPK(a, s0[8], s0[9]);  CVTPK(b, s0[12], s0[13]); PLSWAP(a, b); pk.u[0] = a; pk.u[2] = b;
      CVTPK(a, s0[10], s0[11]); CVTPK(b, s0[14], s0[15]); PLSWAP(a, b); pk.u[1] = a; pk.u[3] = b;
      pa[1] = pk.s;
      CVTPK(a, s1[0], s1[1]);  CVTPK(b, s1[4],  s1[5]);  PLSWAP(a, b); pk.u[0] = a; pk.u[2] = b;
      CVTPK(a, s1[2], s1[3]);  CVTPK(b, s1[6],  s1[7]);  PLSWAP(a, b); pk.u[1] = a; pk.u[3] = b;
      pa[2] = pk.s;
      CVTPK(a, s1[8], s1[9]);  CVTPK(b, s1[12], s1[13]); PLSWAP(a, b); pk.u[0] = a; pk.u[2] = b;
      CVTPK(a, s1[10], s1[11]); CVTPK(b, s1[14], s1[15]); PLSWAP(a, b); pk.u[1] = a; pk.u[3] = b;
      pa[3] = pk.s;
    }

    // ---- PV: O^T[d][q] += V^T-frag x P-frag ----
    __builtin_amdgcn_s_setprio(1);
    #pragma unroll
    for (int dt = 0; dt < 3; ++dt){
      #pragma unroll
      for (int w = 0; w < 4; ++w){
        short8 vf = *(const short8*)(Vb + dt * 2304 + w * 16);
        oacc[dt] = MFMA32(vf, pa[w], oacc[dt]);
      }
    }
    __builtin_amdgcn_s_setprio(0);

    // ---- stage next tile into the other buffer ----
    if (kt < 63){
      const int nb = cur ^ 1;
      #pragma unroll
      for (int j = 0; j < 3; ++j) *(short8*)(lds + loff[j] + nb * lstep[j]) = rs[j];
    }
  }

  // epilogue: combine lane^32 denominators (one shfl), normalize, write bf16 [B][N][C]
  float lt = lsum + __shfl_xor(lsum, 32, 64);
  float inv = 1.0f / lt;
  int b_ = bh >> 3, h = bh & 7;
  unsigned short* orow = ao + (size_t)(b_ * 4096 + q0 + qc) * 768 + h * 96;
  #pragma unroll
  for (int dt = 0; dt < 3; ++dt)
    #pragma unroll
    for (int g = 0; g < 4; ++g){
      short4v sv;
      #pragma unroll
      for (int r = 0; r < 4; ++r) sv[r] = (short)f2b_rne(oacc[dt][g * 4 + r] * inv);
      *(short4v*)(orow + dt * 32 + g * 8 + hi * 4) = sv;
    }
#undef CVTPK
#undef PLSWAP
}

// ---------------- proj GEMM: ao[8192][768] @ wprojt[768][768]^T + bias -> f32 out ----------------
__global__ __launch_bounds__(256) void k_gemm_proj(
    const unsigned short* __restrict__ A,
    const unsigned short* __restrict__ Bt,
    const float* __restrict__ bias,
    float* __restrict__ out)
{
  __shared__ short As[128 * 40];
  __shared__ short Bs[128 * 40];
  int m0 = blockIdx.x * 128, n0 = blockIdx.y * 128;
  int t = threadIdx.x, l = t & 63, w = t >> 6;
  int lr = l & 15, lh = l >> 4;
  int wr = w >> 1, wc = w & 1;

  int row0 = t >> 2, cs0 = t & 3;
  int row1 = row0 + 64;
  const unsigned short* ga0 = A  + (size_t)(m0 + row0) * 768 + cs0 * 8;
  const unsigned short* ga1 = A  + (size_t)(m0 + row1) * 768 + cs0 * 8;
  const unsigned short* gb0 = Bt + (size_t)(n0 + row0) * 768 + cs0 * 8;
  const unsigned short* gb1 = Bt + (size_t)(n0 + row1) * 768 + cs0 * 8;
  short* la0 = As + row0 * 40 + cs0 * 8;
  short* la1 = As + row1 * 40 + cs0 * 8;
  short* lb0 = Bs + row0 * 40 + cs0 * 8;
  short* lb1 = Bs + row1 * 40 + cs0 * 8;

  f32x4 acc[4][4];
  f32x4 z4 = {0.f, 0.f, 0.f, 0.f};
  #pragma unroll
  for (int mf = 0; mf < 4; ++mf)
    #pragma unroll
    for (int nf = 0; nf < 4; ++nf) acc[mf][nf] = z4;

  short8 ra0 = *(const short8*)ga0;
  short8 ra1 = *(const short8*)ga1;
  short8 rb0 = *(const short8*)gb0;
  short8 rb1 = *(const short8*)gb1;

  for (int kt = 0; kt < 24; ++kt){
    __syncthreads();
    *(short8*)la0 = ra0; *(short8*)la1 = ra1;
    *(short8*)lb0 = rb0; *(short8*)lb1 = rb1;
    __syncthreads();
    if (kt < 23){
      ra0 = *(const short8*)(ga0 + (kt + 1) * 32);
      ra1 = *(const short8*)(ga1 + (kt + 1) * 32);
      rb0 = *(const short8*)(gb0 + (kt + 1) * 32);
      rb1 = *(const short8*)(gb1 + (kt + 1) * 32);
    }
    short8 af[4], bfm[4];
    #pragma unroll
    for (int mf = 0; mf < 4; ++mf)
      af[mf] = *(const short8*)(As + (wr * 64 + mf * 16 + lr) * 40 + lh * 8);
    #pragma unroll
    for (int nf = 0; nf < 4; ++nf)
      bfm[nf] = *(const short8*)(Bs + (wc * 64 + nf * 16 + lr) * 40 + lh * 8);
    #pragma unroll
    for (int mf = 0; mf < 4; ++mf)
      #pragma unroll
      for (int nf = 0; nf < 4; ++nf)
        acc[mf][nf] = MFMA16(af[mf], bfm[nf], acc[mf][nf]);
  }

  #pragma unroll
  for (int nf = 0; nf < 4; ++nf){
    int gcol = n0 + wc * 64 + nf * 16 + lr;
    float bb = bias[gcol];
    #pragma unroll
    for (int mf = 0; mf < 4; ++mf){
      int grow = m0 + wr * 64 + mf * 16 + lh * 4;
      #pragma unroll
      for (int r = 0; r < 4; ++r)
        out[(size_t)(grow + r) * 768 + gcol] = acc[mf][nf][r] + bb;
    }
  }
}

extern "C" void kernel_launch(void* const* d_in, const int* in_sizes, int n_in,
                              void* d_out, int out_size, void* d_ws, size_t ws_size,
                              hipStream_t stream) {
  const float* x      = (const float*)d_in[0];
  const float* w_qkv  = (const float*)d_in[1];
  const float* w_proj = (const float*)d_in[2];
  const float* b_proj = (const float*)d_in[3];
  float* out = (float*)d_out;
  char* ws = (char*)d_ws;

  // workspace layout (all 16B-aligned); aob lives where xb used to (x now read directly)
  unsigned short* aob    = (unsigned short*)(ws);                 // 12,582,912 B
  unsigned short* wqkvt  = (unsigned short*)(ws + 12582912);      //  3,538,944 B
  unsigned short* wprojt = (unsigned short*)(ws + 16121856);      //  1,179,648 B
  unsigned short* qbuf   = (unsigned short*)(ws + 17301504);      // 12,582,912 B
  unsigned short* kbuf   = (unsigned short*)(ws + 29884416);      // 12,582,912 B
  unsigned short* vtb    = (unsigned short*)(ws + 42467328);      // 12,582,912 B

  k_transpose_cvt2<<<dim3(72, 24, 2), dim3(32, 8), 0, stream>>>(w_qkv, w_proj, wqkvt, wprojt);
  k_gemm_qkv<<<dim3(64, 18), 256, 0, stream>>>(x, wqkvt, qbuf, kbuf, vtb);
  k_attn12<<<dim3(16, 16), 512, 0, stream>>>(qbuf, kbuf, vtb, aob);
  k_gemm_proj<<<dim3(64, 6), 256, 0, stream>>>(aob, wprojt, b_proj, out);
}